// Round 1
// baseline (427.628 us; speedup 1.0000x reference)
//
#include <hip/hip_runtime.h>
#include <hip/hip_bf16.h>
#include <stdint.h>

// Problem constants (fixed by reference): B=4, S=128 -> M=512
#define M_DIM 512
#define K_DIM 4096
#define N_DIM 11008
#define BM 128
#define BN 128
#define BK 64
#define KT (K_DIM / BK)   // 64 k-tiles
#define NBLK ((M_DIM / BM) * (N_DIM / BN))  // 4 * 86 = 344

typedef __attribute__((ext_vector_type(8))) short bf16x8;   // 8 bf16 = 4 VGPRs (guide-verified)
typedef __attribute__((ext_vector_type(4))) float floatx4;

// round-half-up fp32->bf16, pack two into one uint (lo = a, hi = b)
__device__ __forceinline__ unsigned int pack_bf16(float a, float b) {
    union { float f; unsigned int u; } ua, ub;
    ua.f = a; ub.f = b;
    unsigned int x = ua.u + 0x8000u;
    unsigned int y = ub.u + 0x8000u;
    return (x >> 16) | (y & 0xFFFF0000u);
}

// ---------------------------------------------------------------------------
// Kernel 1: x fp32 [512,4096] -> bf16, stored tile-major (128x64 tiles) with
// per-row chunk rotation: element (r, c*8+j) of a tile lands at
//   r*64 + ((c + r) & 7)*8 + j     (chunks = 16B groups of 8 bf16)
// This makes the GEMM's global_load_lds staging a straight linear copy AND
// the MFMA fragment ds_read_b128s bank-conflict-free.
// ---------------------------------------------------------------------------
__global__ __launch_bounds__(256) void cvt_swizzle_kernel(
        const float* __restrict__ x, unsigned int* __restrict__ xb) {
    int id = blockIdx.x * 256 + threadIdx.x;   // chunk id, 512*4096/8 = 262144 total
    int m  = id >> 9;                          // 512 chunks of 8 per row
    int kc = id & 511;
    const float4* src = (const float4*)(x + ((size_t)m << 12) + (kc << 3));
    float4 f0 = src[0];
    float4 f1 = src[1];
    unsigned int u0 = pack_bf16(f0.x, f0.y);
    unsigned int u1 = pack_bf16(f0.z, f0.w);
    unsigned int u2 = pack_bf16(f1.x, f1.y);
    unsigned int u3 = pack_bf16(f1.z, f1.w);
    int tm = m >> 7, r = m & 127, tk = kc >> 3, c = kc & 7;
    int p  = (c + r) & 7;
    // tile = 8192 elements = 4096 uints; within tile: r*32 uints + p*4 uints
    size_t dstu = (((size_t)(tm * KT + tk)) << 12) + (r << 5) + (p << 2);
    uint4 v; v.x = u0; v.y = u1; v.z = u2; v.w = u3;
    *((uint4*)(xb + dstu)) = v;
}

// ---------------------------------------------------------------------------
// Kernel 2: fused dequant + GEMM.  y[m,n] = sum_k x[m,k] * ((q[n,k]-8)*s + z)
// ---------------------------------------------------------------------------
__global__ __launch_bounds__(256, 2) void gemm_w4_kernel(
        const unsigned int* __restrict__ xb,   // swizzled bf16 x
        const int*          __restrict__ wq,   // [N,K] int32 codes 0..15
        const float*        __restrict__ saz,  // [K/128, N, 2]
        float*              __restrict__ out)  // [M,N] fp32
{
    __shared__ __align__(16) unsigned short sA[BM * BK];  // 16 KB, swizzled
    __shared__ __align__(16) unsigned short sW[BN * BK];  // 16 KB, swizzled

    const int tid  = threadIdx.x;
    const int bx   = blockIdx.x;
    const int mb   = bx & 3;        // 4 m-blocks
    const int nb   = bx >> 2;       // 86 n-blocks
    const int wave = tid >> 6;
    const int lane = tid & 63;
    const int q4   = lane >> 4;     // quad
    const int lr   = lane & 15;
    const int wm   = (wave & 1) * 64;
    const int wn   = (wave >> 1) * 64;

    // Precomputed ds_read offsets (shorts) for k-step 0; step 1 = XOR 32.
    int offA[4], offB[4];
#pragma unroll
    for (int t = 0; t < 4; ++t) {
        int rowA = wm + t * 16 + lr;
        offA[t] = rowA * 64 + (((q4 + rowA) & 7) << 3);
        int rowB = wn + t * 16 + lr;
        offB[t] = rowB * 64 + (((q4 + rowB) & 7) << 3);
    }

    floatx4 acc[4][4];
    floatx4 zero4 = {0.f, 0.f, 0.f, 0.f};
#pragma unroll
    for (int i = 0; i < 4; ++i)
#pragma unroll
        for (int j = 0; j < 4; ++j)
            acc[i][j] = zero4;

    // ---- W staging setup: thread t covers row r = t>>1, k-half h = t&1 (32 ints)
    const int r = tid >> 1;
    const int h = tid & 1;
    const int nrow = nb * BN + r;
    const int4* wptr = (const int4*)(wq + (size_t)nrow * K_DIM + h * 32);
    int offW[4];
#pragma unroll
    for (int cc = 0; cc < 4; ++cc) {
        int c = h * 4 + cc;
        offW[cc] = r * 64 + (((c + r) & 7) << 3);
    }

    // ---- A staging: linear copy of pre-swizzled 16 KB tile
    const unsigned int* aptr = xb + (((size_t)(mb * KT)) << 12) + (tid << 2); // uint units
    const unsigned short* ldsA_wavebase = &sA[(size_t)(tid >> 6) << 9];       // wave*1024 B

    for (int kt = 0; kt < KT; ++kt) {
        __syncthreads();

        // A tile: 4 x 16B direct-to-LDS per thread (16 KB total)
#pragma unroll
        for (int i = 0; i < 4; ++i) {
            __builtin_amdgcn_global_load_lds(
                (const __attribute__((address_space(1))) unsigned int*)(aptr + i * 1024),
                (__attribute__((address_space(3))) unsigned int*)(ldsA_wavebase + i * 2048),
                16, 0, 0);
        }

        // W tile: 32 ints -> dequant -> 4 x ds_write_b128
        int4 qv[8];
#pragma unroll
        for (int i = 0; i < 8; ++i) qv[i] = wptr[i];

        const int g = kt >> 1;   // group (GS=128 = 2 k-tiles)
        float2 sz = *((const float2*)(saz + ((size_t)g * N_DIM + nrow) * 2));
        float sc = sz.x;
        float zz = fmaf(-8.f, sc, sz.y);

#pragma unroll
        for (int cc = 0; cc < 4; ++cc) {
            int4 qa = qv[2 * cc];
            int4 qb = qv[2 * cc + 1];
            uint4 v;
            v.x = pack_bf16(fmaf((float)qa.x, sc, zz), fmaf((float)qa.y, sc, zz));
            v.y = pack_bf16(fmaf((float)qa.z, sc, zz), fmaf((float)qa.w, sc, zz));
            v.z = pack_bf16(fmaf((float)qb.x, sc, zz), fmaf((float)qb.y, sc, zz));
            v.w = pack_bf16(fmaf((float)qb.z, sc, zz), fmaf((float)qb.w, sc, zz));
            *((uint4*)&sW[offW[cc]]) = v;
        }
        wptr += 16;       // advance 64 ints
        aptr += 4096;     // advance one 16 KB tile (uints)

        __syncthreads();

        // compute: 2 k-steps of 32, 16 MFMA each
#pragma unroll
        for (int s01 = 0; s01 < 2; ++s01) {
            const int x32 = s01 << 5;   // swizzle: chunk+4 (mod 8) == offset XOR 32 shorts
            bf16x8 av[4], bv[4];
#pragma unroll
            for (int t = 0; t < 4; ++t) {
                av[t] = *((const bf16x8*)&sA[offA[t] ^ x32]);
                bv[t] = *((const bf16x8*)&sW[offB[t] ^ x32]);
            }
#pragma unroll
            for (int i = 0; i < 4; ++i)
#pragma unroll
                for (int j = 0; j < 4; ++j)
                    acc[i][j] = __builtin_amdgcn_mfma_f32_16x16x32_bf16(
                        av[i], bv[j], acc[i][j], 0, 0, 0);
        }
    }

    // Epilogue: C/D layout col = lane&15, row = quad*4 + reg  (m89-verified)
    const int m0 = mb * BM + wm + q4 * 4;
    const int n0 = nb * BN + wn + lr;
#pragma unroll
    for (int i = 0; i < 4; ++i) {
#pragma unroll
        for (int j = 0; j < 4; ++j) {
            floatx4 v = acc[i][j];
            float* o = out + (size_t)(m0 + i * 16) * N_DIM + (n0 + j * 16);
#pragma unroll
            for (int rr = 0; rr < 4; ++rr)
                o[(size_t)rr * N_DIM] = v[rr];
        }
    }
}

extern "C" void kernel_launch(void* const* d_in, const int* in_sizes, int n_in,
                              void* d_out, int out_size, void* d_ws, size_t ws_size,
                              hipStream_t stream) {
    const float* x   = (const float*)d_in[0];
    const int*   wq  = (const int*)d_in[1];
    const float* saz = (const float*)d_in[2];
    // d_in[3] = groupsize (=128), baked into indexing.

    unsigned int* xb = (unsigned int*)d_ws;   // 4 MB swizzled bf16 x

    cvt_swizzle_kernel<<<dim3(1024), dim3(256), 0, stream>>>(x, xb);
    gemm_w4_kernel<<<dim3(NBLK), dim3(256), 0, stream>>>(xb, wq, saz, (float*)d_out);
}

// Round 2
// 423.942 us; speedup vs baseline: 1.0087x; 1.0087x over previous
//
#include <hip/hip_runtime.h>
#include <hip/hip_bf16.h>
#include <stdint.h>

// Problem constants: B=4, S=128 -> M=512
#define M_DIM 512
#define K_DIM 4096
#define N_DIM 11008
#define BM 128
#define BN 128
#define BK 64
#define KT (K_DIM / BK)        // 64 k-tiles
#define SK 2                   // split-K factor
#define KT_PER (KT / SK)       // 32 k-tiles per block
#define NB_N (N_DIM / BN)      // 86
#define NBLK (4 * NB_N * SK)   // 688 blocks

typedef __attribute__((ext_vector_type(8))) short bf16x8;
typedef __attribute__((ext_vector_type(4))) float floatx4;

// fp32 x2 -> packed bf16 (RNE via v_cvt_pk_bf16_f32); lo = a, hi = b
__device__ __forceinline__ unsigned int pack2(float a, float b) {
    union { __hip_bfloat162 h; unsigned int u; } c;
    c.h = __float22bfloat162_rn(float2{a, b});
    return c.u;
}

// ---------------------------------------------------------------------------
// Kernel 1: x fp32 [512,4096] -> bf16, tile-major (128x64 tiles), row-rotated
// 16B chunks: elem (r, c*8+j) -> r*64 + ((c+r)&7)*8 + j.
// ---------------------------------------------------------------------------
__global__ __launch_bounds__(256) void cvt_swizzle_kernel(
        const float* __restrict__ x, unsigned int* __restrict__ xb) {
    int id = blockIdx.x * 256 + threadIdx.x;   // 262144 chunks of 8
    int m  = id >> 9;
    int kc = id & 511;
    const float4* src = (const float4*)(x + ((size_t)m << 12) + (kc << 3));
    float4 f0 = src[0];
    float4 f1 = src[1];
    uint4 v;
    v.x = pack2(f0.x, f0.y);
    v.y = pack2(f0.z, f0.w);
    v.z = pack2(f1.x, f1.y);
    v.w = pack2(f1.z, f1.w);
    int tm = m >> 7, r = m & 127, tk = kc >> 3, c = kc & 7;
    int p  = (c + r) & 7;
    size_t dstu = (((size_t)(tm * KT + tk)) << 12) + (r << 5) + (p << 2);
    *((uint4*)(xb + dstu)) = v;
}

// ---------------------------------------------------------------------------
// Kernel 2: fused dequant + GEMM, split-K=2, double-buffered LDS,
// single barrier per k-iter, register-prefetched W loads.
// ---------------------------------------------------------------------------
__global__ __launch_bounds__(256, 2) void gemm_w4_kernel(
        const unsigned int* __restrict__ xb,
        const int*          __restrict__ wq,
        const float*        __restrict__ saz,
        float*              __restrict__ out)
{
    __shared__ __align__(16) unsigned short sA[2 * BM * BK];  // 32 KB
    __shared__ __align__(16) unsigned short sW[2 * BN * BK];  // 32 KB

    const int tid  = threadIdx.x;
    const int bx   = blockIdx.x;
    const int mb   = bx & 3;
    const int t2   = bx >> 2;          // 0..171
    const int nb   = t2 % NB_N;
    const int sk   = t2 / NB_N;        // 0..1
    const int k0t  = sk * KT_PER;      // first k-tile
    const int wave = tid >> 6;
    const int lane = tid & 63;
    const int q4   = lane >> 4;
    const int lr   = lane & 15;
    const int wm   = (wave & 1) * 64;
    const int wn   = (wave >> 1) * 64;

    // ds_read offsets (shorts) for k-step 0 of a buffer; step 1 = XOR 32.
    int offA[4], offB[4];
#pragma unroll
    for (int t = 0; t < 4; ++t) {
        int rowA = wm + t * 16 + lr;
        offA[t] = rowA * 64 + (((q4 + rowA) & 7) << 3);
        int rowB = wn + t * 16 + lr;
        offB[t] = rowB * 64 + (((q4 + rowB) & 7) << 3);
    }

    floatx4 acc[4][4];
    floatx4 zero4 = {0.f, 0.f, 0.f, 0.f};
#pragma unroll
    for (int i = 0; i < 4; ++i)
#pragma unroll
        for (int j = 0; j < 4; ++j)
            acc[i][j] = zero4;

    // W staging: thread t -> row r = t>>1, k-half h = t&1 (32 ints = 8x int4)
    const int r = tid >> 1;
    const int h = tid & 1;
    const int nrow = nb * BN + r;
    const int4* wptr = (const int4*)(wq + (size_t)nrow * K_DIM + k0t * BK + h * 32);
    int offW[4];
#pragma unroll
    for (int cc = 0; cc < 4; ++cc) {
        int c = h * 4 + cc;
        offW[cc] = r * 64 + (((c + r) & 7) << 3);
    }

    // A staging: linear copy of pre-swizzled 16 KB tiles
    const unsigned int* aptr = xb + (((size_t)(mb * KT + k0t)) << 12) + (tid << 2);
    const int ldsA_wave = (tid >> 6) << 9;   // shorts: wave*1024 B

    // ---- prologue: qv/sz for kt=0, DMA A-tile 0 into buf 0
    int4 qv[8];
#pragma unroll
    for (int i = 0; i < 8; ++i) qv[i] = wptr[i];
    float2 sz = *((const float2*)(saz + ((size_t)(k0t >> 1) * N_DIM + nrow) * 2));
#pragma unroll
    for (int i = 0; i < 4; ++i) {
        __builtin_amdgcn_global_load_lds(
            (const __attribute__((address_space(1))) unsigned int*)(aptr + i * 1024),
            (__attribute__((address_space(3))) unsigned int*)(sA + ldsA_wave + i * 2048),
            16, 0, 0);
    }

    for (int kt = 0; kt < KT_PER; ++kt) {
        const int cur = kt & 1;
        const int curA = cur * (BM * BK);
        const int curW = cur * (BN * BK);

        // dequant current qv -> sW[cur] (before barrier; prior reads of this
        // buffer finished before the previous barrier)
        {
            float sc = sz.x;
            float zz = fmaf(-8.f, sc, sz.y);
#pragma unroll
            for (int cc = 0; cc < 4; ++cc) {
                int4 qa = qv[2 * cc];
                int4 qb = qv[2 * cc + 1];
                uint4 v;
                v.x = pack2(fmaf((float)qa.x, sc, zz), fmaf((float)qa.y, sc, zz));
                v.y = pack2(fmaf((float)qa.z, sc, zz), fmaf((float)qa.w, sc, zz));
                v.z = pack2(fmaf((float)qb.x, sc, zz), fmaf((float)qb.y, sc, zz));
                v.w = pack2(fmaf((float)qb.z, sc, zz), fmaf((float)qb.w, sc, zz));
                *((uint4*)&sW[curW + offW[cc]]) = v;
            }
        }

        __syncthreads();   // drains DMA A[cur] (vmcnt) + W writes (lgkm)

        // prefetch next iteration (qv first so its wait is vmcnt(4), not 0)
        if (kt + 1 < KT_PER) {
            wptr += 16;
#pragma unroll
            for (int i = 0; i < 8; ++i) qv[i] = wptr[i];
            int g = (k0t + kt + 1) >> 1;
            sz = *((const float2*)(saz + ((size_t)g * N_DIM + nrow) * 2));
            aptr += 4096;
            const int nxtA = ((kt + 1) & 1) * (BM * BK);
#pragma unroll
            for (int i = 0; i < 4; ++i) {
                __builtin_amdgcn_global_load_lds(
                    (const __attribute__((address_space(1))) unsigned int*)(aptr + i * 1024),
                    (__attribute__((address_space(3))) unsigned int*)(sA + nxtA + ldsA_wave + i * 2048),
                    16, 0, 0);
            }
        }

        // compute on buffer `cur`: 2 k-steps of 32, 16 MFMA each
#pragma unroll
        for (int s01 = 0; s01 < 2; ++s01) {
            const int x32 = s01 << 5;
            bf16x8 av[4], bv[4];
#pragma unroll
            for (int t = 0; t < 4; ++t) {
                av[t] = *((const bf16x8*)&sA[curA + (offA[t] ^ x32)]);
                bv[t] = *((const bf16x8*)&sW[curW + (offB[t] ^ x32)]);
            }
#pragma unroll
            for (int i = 0; i < 4; ++i)
#pragma unroll
                for (int j = 0; j < 4; ++j)
                    acc[i][j] = __builtin_amdgcn_mfma_f32_16x16x32_bf16(
                        av[i], bv[j], acc[i][j], 0, 0, 0);
        }
    }

    // Epilogue: C/D layout col = lane&15, row = quad*4 + reg; atomic-add
    // partials (out was zeroed by hipMemsetAsync).
    const int m0 = mb * BM + wm + q4 * 4;
    const int n0 = nb * BN + wn + lr;
#pragma unroll
    for (int i = 0; i < 4; ++i) {
#pragma unroll
        for (int j = 0; j < 4; ++j) {
            floatx4 v = acc[i][j];
            float* o = out + (size_t)(m0 + i * 16) * N_DIM + (n0 + j * 16);
#pragma unroll
            for (int rr = 0; rr < 4; ++rr)
                __hip_atomic_fetch_add(&o[(size_t)rr * N_DIM], v[rr],
                                       __ATOMIC_RELAXED, __HIP_MEMORY_SCOPE_AGENT);
        }
    }
}

extern "C" void kernel_launch(void* const* d_in, const int* in_sizes, int n_in,
                              void* d_out, int out_size, void* d_ws, size_t ws_size,
                              hipStream_t stream) {
    const float* x   = (const float*)d_in[0];
    const int*   wq  = (const int*)d_in[1];
    const float* saz = (const float*)d_in[2];

    unsigned int* xb = (unsigned int*)d_ws;   // 4 MB swizzled bf16 x

    hipMemsetAsync(d_out, 0, (size_t)out_size * sizeof(float), stream);
    cvt_swizzle_kernel<<<dim3(1024), dim3(256), 0, stream>>>(x, xb);
    gemm_w4_kernel<<<dim3(NBLK), dim3(256), 0, stream>>>(xb, wq, saz, (float*)d_out);
}

// Round 4
// 387.703 us; speedup vs baseline: 1.1030x; 1.0935x over previous
//
#include <hip/hip_runtime.h>
#include <hip/hip_fp16.h>
#include <stdint.h>

// Problem constants: B=4, S=128 -> M=512
#define M_DIM 512
#define K_DIM 4096
#define N_DIM 11008
#define BM 128
#define BN 128
#define BK 64
#define KT (K_DIM / BK)        // 64 k-tiles
#define NB_N (N_DIM / BN)      // 86
#define SK 3                   // split-K (1032 blocks = 2.016 rounds of 512)
#define NBLK (4 * NB_N * SK)

typedef __attribute__((ext_vector_type(8))) _Float16 half8;
typedef __attribute__((ext_vector_type(4))) float floatx4;

__device__ __forceinline__ unsigned int h2u(__half2 h) {
    union { __half2 h; unsigned int u; } c; c.h = h; return c.u;
}
__device__ __forceinline__ __half2 u2h(unsigned int u) {
    union { unsigned int u; __half2 h; } c; c.u = u; return c.h;
}

// ---------------------------------------------------------------------------
// Kernel 1: x fp32 [512,4096] -> f16, tile-major (128x64 tiles), row-rotated
// 16B chunks: elem (r, c*8+j) -> r*64 + ((c+r)&7)*8 + j.
// ---------------------------------------------------------------------------
__global__ __launch_bounds__(256) void cvt_kernel(
        const float* __restrict__ x, unsigned int* __restrict__ xb) {
    int id = blockIdx.x * 256 + threadIdx.x;   // 262144 chunks of 8
    int m  = id >> 9;
    int kc = id & 511;
    const float4* src = (const float4*)(x + ((size_t)m << 12) + (kc << 3));
    float4 f0 = src[0];
    float4 f1 = src[1];
    uint4 v;
    v.x = h2u(__float22half2_rn(float2{f0.x, f0.y}));
    v.y = h2u(__float22half2_rn(float2{f0.z, f0.w}));
    v.z = h2u(__float22half2_rn(float2{f1.x, f1.y}));
    v.w = h2u(__float22half2_rn(float2{f1.z, f1.w}));
    int tm = m >> 7, r = m & 127, tk = kc >> 3, c = kc & 7;
    int p  = (c + r) & 7;
    size_t dstu = (((size_t)(tm * KT + tk)) << 12) + (r << 5) + (p << 2);
    *((uint4*)(xb + dstu)) = v;
}

// ---------------------------------------------------------------------------
// Kernel 2: pack wq int32 [N,K] codes -> 4-bit nibbles, GEMM-tile-major.
// Tile (nb, kt) = rows nb*128..+127 x codes kt*64..+63 = 1024 dwords (4 KB).
// Dword d = r*8 + q covers codes q*8..q*8+7 of row r; nibble order:
// code 2j -> bits 4j, code 2j+1 -> bits 16+4j (pair trick).
// ---------------------------------------------------------------------------
__global__ __launch_bounds__(256) void pack_kernel(
        const int* __restrict__ wq, unsigned int* __restrict__ wpk) {
    int id   = blockIdx.x * 256 + threadIdx.x;  // pair id, 2,818,048 total
    int tile = id >> 9;                         // 5504 tiles (86 nb x 64 kt)
    int p    = id & 511;
    int nb = tile >> 6, kt = tile & 63;
    int r = p >> 2, q0 = (p & 3) * 2;
    const int4* src = (const int4*)(wq + (size_t)(nb * 128 + r) * K_DIM + kt * 64 + q0 * 8);
    int4 a0 = src[0];
    int4 a1 = src[1];
    int4 a2 = src[2];
    int4 a3 = src[3];
    unsigned int u0 =
        (unsigned)a0.x | ((unsigned)a0.z << 4)  | ((unsigned)a1.x << 8)  | ((unsigned)a1.z << 12) |
        ((unsigned)a0.y << 16) | ((unsigned)a0.w << 20) | ((unsigned)a1.y << 24) | ((unsigned)a1.w << 28);
    unsigned int u1 =
        (unsigned)a2.x | ((unsigned)a2.z << 4)  | ((unsigned)a3.x << 8)  | ((unsigned)a3.z << 12) |
        ((unsigned)a2.y << 16) | ((unsigned)a2.w << 20) | ((unsigned)a3.y << 24) | ((unsigned)a3.w << 28);
    uint2 o; o.x = u0; o.y = u1;
    *((uint2*)(wpk + (((size_t)tile) << 10) + (p << 1))) = o;
}

// ---------------------------------------------------------------------------
// Kernel 3: GEMM, f16 MFMA, packed-int4 weights (L2-resident), split-K=3,
// double-buffered LDS, single barrier/iter, atomic-f32 epilogue.
// ---------------------------------------------------------------------------
__global__ __launch_bounds__(256, 2) void gemm_kernel(
        const unsigned int* __restrict__ xb,    // swizzled f16 x, tile-major
        const unsigned int* __restrict__ wpk,   // packed nibbles, tile-major
        const float*        __restrict__ saz,   // [K/128, N, 2]
        float*              __restrict__ out)   // [M,N] fp32 (pre-zeroed)
{
    __shared__ __align__(16) unsigned short sA[2 * BM * BK];  // 32 KB
    __shared__ __align__(16) unsigned short sW[2 * BN * BK];  // 32 KB

    const int tid = threadIdx.x;
    const int bx  = blockIdx.x;
    const int mb  = bx & 3;
    const int t2  = bx >> 2;
    const int nb  = t2 % NB_N;
    const int sk  = t2 / NB_N;
    const int kt0 = (sk * KT) / SK;            // 0, 21, 42
    const int kt1 = ((sk + 1) * KT) / SK;      // 21, 42, 64
    const int wave = tid >> 6;
    const int lane = tid & 63;
    const int q4   = lane >> 4;
    const int lr   = lane & 15;
    const int wm   = (wave & 1) * 64;
    const int wn   = (wave >> 1) * 64;

    // ds_read offsets (shorts) for k-step 0; step 1 = XOR 32 (chunk+4 mod 8).
    int offA[4], offB[4];
#pragma unroll
    for (int t = 0; t < 4; ++t) {
        int rowA = wm + t * 16 + lr;
        offA[t] = rowA * 64 + (((q4 + rowA) & 7) << 3);
        int rowB = wn + t * 16 + lr;
        offB[t] = rowB * 64 + (((q4 + rowB) & 7) << 3);
    }

    floatx4 acc[4][4];
    floatx4 zero4 = {0.f, 0.f, 0.f, 0.f};
#pragma unroll
    for (int i = 0; i < 4; ++i)
#pragma unroll
        for (int j = 0; j < 4; ++j)
            acc[i][j] = zero4;

    // W staging: thread covers row r = tid>>1, octet group q0 = (tid&1)*4
    // (one uint4 of packed dwords = 32 codes = 4 LDS chunks).
    const int r = tid >> 1;
    const int nrow = nb * BN + r;
    // Tile stride = 1024 dwords = 256 uint4.  (R3 bug: advanced 1 uint4/tile.)
    const uint4* wptr = (const uint4*)wpk + (((size_t)(nb * KT + kt0)) << 8) + tid;
    int offW[4];
#pragma unroll
    for (int cc = 0; cc < 4; ++cc) {
        int c = (tid & 1) * 4 + cc;
        offW[cc] = r * 64 + (((c + r) & 7) << 3);
    }

    // A staging: linear DMA of pre-swizzled 16 KB tiles
    const unsigned int* aptr = xb + (((size_t)(mb * KT + kt0)) << 12) + (tid << 2);
    const int ldsA_wave = (tid >> 6) << 9;     // shorts

    // ---- prologue
    uint4 qw = wptr[0];
    float2 sz = *((const float2*)(saz + ((size_t)(kt0 >> 1) * N_DIM + nrow) * 2));
#pragma unroll
    for (int i = 0; i < 4; ++i) {
        __builtin_amdgcn_global_load_lds(
            (const __attribute__((address_space(1))) unsigned int*)(aptr + i * 1024),
            (__attribute__((address_space(3))) unsigned int*)(sA + ldsA_wave + i * 2048),
            16, 0, 0);
    }

    for (int kt = kt0; kt < kt1; ++kt) {
        const int cur  = (kt - kt0) & 1;
        const int curA = cur * (BM * BK);
        const int curW = cur * (BN * BK);

        // dequant qw -> sW[cur]: per dword, 4 f16-pairs via pk math.
        {
            float sc  = sz.x;
            float zzf = fmaf(-8.f, sc, sz.y);
            __half2 s2 = __float2half2_rn(sc);
            __half2 z2 = __float2half2_rn(zzf);
            const __half2 kb = u2h(0x64006400u);   // (1024, 1024)
            unsigned int dws[4] = {qw.x, qw.y, qw.z, qw.w};
#pragma unroll
            for (int cc = 0; cc < 4; ++cc) {
                unsigned int dw = dws[cc];
                unsigned int e[4];
#pragma unroll
                for (int j = 0; j < 4; ++j) {
                    unsigned int pr = ((dw >> (4 * j)) & 0x000F000Fu) | 0x64006400u;
                    __half2 h = __hsub2(u2h(pr), kb);     // exact (q2j, q2j+1)
                    h = __hfma2(h, s2, z2);               // q*s + (z-8s)
                    e[j] = h2u(h);
                }
                uint4 v; v.x = e[0]; v.y = e[1]; v.z = e[2]; v.w = e[3];
                *((uint4*)&sW[curW + offW[cc]]) = v;
            }
        }

        __syncthreads();   // drains A-DMA[cur] + W writes

        // prefetch next iter (qw/saz first -> compiler waits vmcnt(>0))
        if (kt + 1 < kt1) {
            wptr += 256;                       // next k-tile (256 uint4)
            qw = wptr[0];
            sz = *((const float2*)(saz + ((size_t)((kt + 1) >> 1) * N_DIM + nrow) * 2));
            aptr += 4096;
            const int nxtA = ((kt - kt0 + 1) & 1) * (BM * BK);
#pragma unroll
            for (int i = 0; i < 4; ++i) {
                __builtin_amdgcn_global_load_lds(
                    (const __attribute__((address_space(1))) unsigned int*)(aptr + i * 1024),
                    (__attribute__((address_space(3))) unsigned int*)(sA + nxtA + ldsA_wave + i * 2048),
                    16, 0, 0);
            }
        }

        // compute on `cur`: 2 k-steps of 32, 16 MFMA each
#pragma unroll
        for (int s01 = 0; s01 < 2; ++s01) {
            const int x32 = s01 << 5;
            half8 av[4], bv[4];
#pragma unroll
            for (int t = 0; t < 4; ++t) {
                av[t] = *((const half8*)&sA[curA + (offA[t] ^ x32)]);
                bv[t] = *((const half8*)&sW[curW + (offB[t] ^ x32)]);
            }
#pragma unroll
            for (int i = 0; i < 4; ++i)
#pragma unroll
                for (int j = 0; j < 4; ++j)
                    acc[i][j] = __builtin_amdgcn_mfma_f32_16x16x32_f16(
                        av[i], bv[j], acc[i][j], 0, 0, 0);
        }
    }

    // Epilogue: C/D layout col = lane&15, row = quad*4 + reg; atomic partials.
    const int m0 = mb * BM + wm + q4 * 4;
    const int n0 = nb * BN + wn + lr;
#pragma unroll
    for (int i = 0; i < 4; ++i) {
#pragma unroll
        for (int j = 0; j < 4; ++j) {
            floatx4 v = acc[i][j];
            float* o = out + (size_t)(m0 + i * 16) * N_DIM + (n0 + j * 16);
#pragma unroll
            for (int rr = 0; rr < 4; ++rr)
                __hip_atomic_fetch_add(&o[(size_t)rr * N_DIM], v[rr],
                                       __ATOMIC_RELAXED, __HIP_MEMORY_SCOPE_AGENT);
        }
    }
}

extern "C" void kernel_launch(void* const* d_in, const int* in_sizes, int n_in,
                              void* d_out, int out_size, void* d_ws, size_t ws_size,
                              hipStream_t stream) {
    const float* x   = (const float*)d_in[0];
    const int*   wq  = (const int*)d_in[1];
    const float* saz = (const float*)d_in[2];

    // ws layout: [wpk: 22,544,384 B packed weights][xb: 4 MB f16 x]
    unsigned int* wpk = (unsigned int*)d_ws;
    unsigned int* xb  = (unsigned int*)((char*)d_ws + 22544384);

    hipMemsetAsync(d_out, 0, (size_t)out_size * sizeof(float), stream);
    pack_kernel<<<dim3(11008), dim3(256), 0, stream>>>(wq, wpk);
    cvt_kernel<<<dim3(1024), dim3(256), 0, stream>>>(x, xb);
    gemm_kernel<<<dim3(NBLK), dim3(256), 0, stream>>>(xb, wpk, saz, (float*)d_out);
}

// Round 5
// 372.056 us; speedup vs baseline: 1.1494x; 1.0421x over previous
//
#include <hip/hip_runtime.h>
#include <hip/hip_fp16.h>
#include <stdint.h>

// Problem constants: B=4, S=128 -> M=512
#define M_DIM 512
#define K_DIM 4096
#define N_DIM 11008
#define BM 128
#define BN 128
#define BK 64
#define KT (K_DIM / BK)        // 64 k-tiles
#define NB_N (N_DIM / BN)      // 86
#define SK 3                   // 1032 blocks ~= 1024 resident at 4 blocks/CU
#define NBLK (4 * NB_N * SK)

typedef __attribute__((ext_vector_type(8))) _Float16 half8;
typedef __attribute__((ext_vector_type(4))) float floatx4;

__device__ __forceinline__ unsigned int h2u(__half2 h) {
    union { __half2 h; unsigned int u; } c; c.h = h; return c.u;
}
__device__ __forceinline__ __half2 u2h(unsigned int u) {
    union { unsigned int u; __half2 h; } c; c.u = u; return c.h;
}
union U4H8 { uint4 u; half8 h; };

// one packed dword (8 codes, pair-interleaved) -> b-operand half8
__device__ __forceinline__ half8 dequant8(unsigned int dw, __half2 s2, __half2 z2) {
    const __half2 kb = u2h(0x64006400u);   // (1024, 1024)
    U4H8 r;
    unsigned int p0 = (dw & 0x000F000Fu) | 0x64006400u;
    unsigned int p1 = ((dw >> 4)  & 0x000F000Fu) | 0x64006400u;
    unsigned int p2 = ((dw >> 8)  & 0x000F000Fu) | 0x64006400u;
    unsigned int p3 = ((dw >> 12) & 0x000F000Fu) | 0x64006400u;
    r.u.x = h2u(__hfma2(__hsub2(u2h(p0), kb), s2, z2));
    r.u.y = h2u(__hfma2(__hsub2(u2h(p1), kb), s2, z2));
    r.u.z = h2u(__hfma2(__hsub2(u2h(p2), kb), s2, z2));
    r.u.w = h2u(__hfma2(__hsub2(u2h(p3), kb), s2, z2));
    return r.h;
}

// ---------------------------------------------------------------------------
// Kernel 1: x fp32 [512,4096] -> f16, tile-major (128x64 tiles), row-rotated
// 16B chunks: elem (r, c*8+j) -> r*64 + ((c+r)&7)*8 + j.
// ---------------------------------------------------------------------------
__global__ __launch_bounds__(256) void cvt_kernel(
        const float* __restrict__ x, unsigned int* __restrict__ xb) {
    int id = blockIdx.x * 256 + threadIdx.x;
    int m  = id >> 9;
    int kc = id & 511;
    const float4* src = (const float4*)(x + ((size_t)m << 12) + (kc << 3));
    float4 f0 = src[0];
    float4 f1 = src[1];
    uint4 v;
    v.x = h2u(__float22half2_rn(float2{f0.x, f0.y}));
    v.y = h2u(__float22half2_rn(float2{f0.z, f0.w}));
    v.z = h2u(__float22half2_rn(float2{f1.x, f1.y}));
    v.w = h2u(__float22half2_rn(float2{f1.z, f1.w}));
    int tm = m >> 7, r = m & 127, tk = kc >> 3, c = kc & 7;
    int p  = (c + r) & 7;
    size_t dstu = (((size_t)(tm * KT + tk)) << 12) + (r << 5) + (p << 2);
    *((uint4*)(xb + dstu)) = v;
}

// ---------------------------------------------------------------------------
// Kernel 2: pack wq int32 [N,K] -> nibbles, tile-major [nb][kt], within tile
// dword index = q*128 + r  (q = k-octet 0..7, r = n-row 0..127), nibble
// order pair-interleaved: code 2j -> bits 4j, code 2j+1 -> bits 16+4j.
// This makes a GEMM b-fragment load = 4 fully-used 64 B segments.
// ---------------------------------------------------------------------------
__global__ __launch_bounds__(256) void pack_kernel(
        const int* __restrict__ wq, unsigned int* __restrict__ wpk) {
    int id   = blockIdx.x * 256 + threadIdx.x;
    int tile = id >> 9;                         // 5504 tiles (86 nb x 64 kt)
    int p    = id & 511;
    int nb = tile >> 6, kt = tile & 63;
    int r = p >> 2, q0 = (p & 3) * 2;
    const int4* src = (const int4*)(wq + (size_t)(nb * 128 + r) * K_DIM + kt * 64 + q0 * 8);
    int4 a0 = src[0];
    int4 a1 = src[1];
    int4 a2 = src[2];
    int4 a3 = src[3];
    unsigned int u0 =
        (unsigned)a0.x | ((unsigned)a0.z << 4)  | ((unsigned)a1.x << 8)  | ((unsigned)a1.z << 12) |
        ((unsigned)a0.y << 16) | ((unsigned)a0.w << 20) | ((unsigned)a1.y << 24) | ((unsigned)a1.w << 28);
    unsigned int u1 =
        (unsigned)a2.x | ((unsigned)a2.z << 4)  | ((unsigned)a3.x << 8)  | ((unsigned)a3.z << 12) |
        ((unsigned)a2.y << 16) | ((unsigned)a2.w << 20) | ((unsigned)a3.y << 24) | ((unsigned)a3.w << 28);
    size_t base = ((size_t)tile) << 10;
    wpk[base + (q0 << 7) + r]       = u0;   // octet q0
    wpk[base + ((q0 + 1) << 7) + r] = u1;   // octet q0+1
}

// ---------------------------------------------------------------------------
// Kernel 3: GEMM. A via LDS (double-buffered, DMA); W dequanted directly
// from packed dwords into b-operand registers (NO LDS for W). Split-K=3,
// single barrier/iter, atomic-f32 epilogue.
// ---------------------------------------------------------------------------
__global__ __launch_bounds__(256, 4) void gemm_kernel(
        const unsigned int* __restrict__ xb,    // swizzled f16 x, tile-major
        const unsigned int* __restrict__ wpk,   // packed nibbles, [q][r] tiles
        const float*        __restrict__ saz,   // [K/128, N, 2]
        float*              __restrict__ out)   // [M,N] fp32 (pre-zeroed)
{
    __shared__ __align__(16) unsigned short sA[2 * BM * BK];  // 32 KB (A only)

    const int tid = threadIdx.x;
    const int bx  = blockIdx.x;
    const int mb  = bx & 3;
    const int t2  = bx >> 2;
    const int nb  = t2 % NB_N;
    const int sk  = t2 / NB_N;
    const int kt0 = (sk * KT) / SK;            // 0, 21, 42
    const int kt1 = ((sk + 1) * KT) / SK;      // 21, 42, 64
    const int wave = tid >> 6;
    const int lane = tid & 63;
    const int q4   = lane >> 4;
    const int lr   = lane & 15;
    const int wm   = (wave & 1) * 64;
    const int wn   = (wave >> 1) * 64;

    // A ds_read offsets (shorts) for k-step 0; step 1 = XOR 32.
    int offA[4];
#pragma unroll
    for (int t = 0; t < 4; ++t) {
        int rowA = wm + t * 16 + lr;
        offA[t] = rowA * 64 + (((q4 + rowA) & 7) << 3);
    }

    floatx4 acc[4][4];
    floatx4 zero4 = {0.f, 0.f, 0.f, 0.f};
#pragma unroll
    for (int i = 0; i < 4; ++i)
#pragma unroll
        for (int j = 0; j < 4; ++j)
            acc[i][j] = zero4;

    // W fragment addressing: tile base + q4*128 + wn + lr; frag (j,s01) at
    // + s01*512 + j*16.
    const unsigned int* wbase =
        wpk + (((size_t)(nb * KT + kt0)) << 10) + (q4 << 7) + wn + lr;

    // scale addressing: n-row for frag j = nrow0 + j*16
    const float2* saz2 = (const float2*)saz;
    const int nrow0 = nb * BN + wn + lr;

    // A staging: linear DMA of pre-swizzled 16 KB tiles
    const unsigned int* aptr = xb + (((size_t)(mb * KT + kt0)) << 12) + (tid << 2);
    const int ldsA_wave = (tid >> 6) << 9;     // shorts

    // ---- prologue: W dwords + scales for kt0, DMA A-tile kt0 into buf 0
    unsigned int qw[8], qwn[8];
#pragma unroll
    for (int f = 0; f < 8; ++f)
        qw[f] = wbase[(f >> 2) * 512 + (f & 3) * 16];

    __half2 s2[4], z2[4];
#pragma unroll
    for (int t = 0; t < 4; ++t) {
        float2 f = saz2[(size_t)(kt0 >> 1) * N_DIM + nrow0 + t * 16];
        s2[t] = __float2half2_rn(f.x);
        z2[t] = __float2half2_rn(fmaf(-8.f, f.x, f.y));
    }
    float2 szn[4];

#pragma unroll
    for (int i = 0; i < 4; ++i) {
        __builtin_amdgcn_global_load_lds(
            (const __attribute__((address_space(1))) unsigned int*)(aptr + i * 1024),
            (__attribute__((address_space(3))) unsigned int*)(sA + ldsA_wave + i * 2048),
            16, 0, 0);
    }

    for (int kt = kt0; kt < kt1; ++kt) {
        const int it   = kt - kt0;
        const int curA = (it & 1) * (BM * BK);

        // group changes on even kt: convert scales prefetched last iter
        if (it > 0 && (kt & 1) == 0) {
#pragma unroll
            for (int t = 0; t < 4; ++t) {
                s2[t] = __float2half2_rn(szn[t].x);
                z2[t] = __float2half2_rn(fmaf(-8.f, szn[t].x, szn[t].y));
            }
        }

        __syncthreads();   // sA[cur] DMA (prev iter) now visible

        // prefetch next k-tile: W dwords, scales (if new group), A-DMA
        if (kt + 1 < kt1) {
            wbase += 1024;
#pragma unroll
            for (int f = 0; f < 8; ++f)
                qwn[f] = wbase[(f >> 2) * 512 + (f & 3) * 16];
            if (((kt + 1) & 1) == 0) {
#pragma unroll
                for (int t = 0; t < 4; ++t)
                    szn[t] = saz2[(size_t)((kt + 1) >> 1) * N_DIM + nrow0 + t * 16];
            }
            aptr += 4096;
            const int nxtA = ((it + 1) & 1) * (BM * BK);
#pragma unroll
            for (int i = 0; i < 4; ++i) {
                __builtin_amdgcn_global_load_lds(
                    (const __attribute__((address_space(1))) unsigned int*)(aptr + i * 1024),
                    (__attribute__((address_space(3))) unsigned int*)(sA + nxtA + ldsA_wave + i * 2048),
                    16, 0, 0);
            }
        }

        // compute: 2 k-steps of 32; dequant b-frags in registers
#pragma unroll
        for (int s01 = 0; s01 < 2; ++s01) {
            const int x32 = s01 << 5;
            half8 av[4];
#pragma unroll
            for (int t = 0; t < 4; ++t)
                av[t] = *((const half8*)&sA[curA + (offA[t] ^ x32)]);
#pragma unroll
            for (int j = 0; j < 4; ++j) {
                half8 bv = dequant8(qw[s01 * 4 + j], s2[j], z2[j]);
#pragma unroll
                for (int i = 0; i < 4; ++i)
                    acc[i][j] = __builtin_amdgcn_mfma_f32_16x16x32_f16(
                        av[i], bv, acc[i][j], 0, 0, 0);
            }
        }

#pragma unroll
        for (int f = 0; f < 8; ++f) qw[f] = qwn[f];
    }

    // Epilogue: C/D layout col = lane&15 (n), row = quad*4 + reg (m).
    const int m0 = mb * BM + wm + q4 * 4;
    const int n0 = nb * BN + wn + lr;
#pragma unroll
    for (int i = 0; i < 4; ++i) {
#pragma unroll
        for (int j = 0; j < 4; ++j) {
            floatx4 v = acc[i][j];
            float* o = out + (size_t)(m0 + i * 16) * N_DIM + (n0 + j * 16);
#pragma unroll
            for (int rr = 0; rr < 4; ++rr)
                __hip_atomic_fetch_add(&o[(size_t)rr * N_DIM], v[rr],
                                       __ATOMIC_RELAXED, __HIP_MEMORY_SCOPE_AGENT);
        }
    }
}

extern "C" void kernel_launch(void* const* d_in, const int* in_sizes, int n_in,
                              void* d_out, int out_size, void* d_ws, size_t ws_size,
                              hipStream_t stream) {
    const float* x   = (const float*)d_in[0];
    const int*   wq  = (const int*)d_in[1];
    const float* saz = (const float*)d_in[2];

    // ws layout: [wpk: 22,544,384 B packed weights][xb: 4 MB f16 x]
    unsigned int* wpk = (unsigned int*)d_ws;
    unsigned int* xb  = (unsigned int*)((char*)d_ws + 22544384);

    hipMemsetAsync(d_out, 0, (size_t)out_size * sizeof(float), stream);
    pack_kernel<<<dim3(11008), dim3(256), 0, stream>>>(wq, wpk);
    cvt_kernel<<<dim3(1024), dim3(256), 0, stream>>>(x, xb);
    gemm_kernel<<<dim3(NBLK), dim3(256), 0, stream>>>(xb, wpk, saz, (float*)d_out);
}

// Round 6
// 359.022 us; speedup vs baseline: 1.1911x; 1.0363x over previous
//
#include <hip/hip_runtime.h>
#include <hip/hip_fp16.h>
#include <stdint.h>

// Problem constants: B=4, S=128 -> M=512
#define M_DIM 512
#define K_DIM 4096
#define N_DIM 11008
#define KT (K_DIM / 64)        // 64 k-tiles of BK=64
#define SK 2                   // split-K
#define NB_M 8                 // 64-row strips
#define NB_N 172               // 64-col strips
#define NBLK (NB_M * NB_N * SK)   // 2752 single-wave blocks

typedef __attribute__((ext_vector_type(8))) _Float16 half8;
typedef __attribute__((ext_vector_type(4))) float floatx4;

__device__ __forceinline__ unsigned int h2u(__half2 h) {
    union { __half2 h; unsigned int u; } c; c.h = h; return c.u;
}
__device__ __forceinline__ __half2 u2h(unsigned int u) {
    union { unsigned int u; __half2 h; } c; c.u = u; return c.h;
}
union U4H8 { uint4 u; half8 h; };

// one packed dword (8 codes, pair-interleaved) -> b-operand half8 (R5-proven)
__device__ __forceinline__ half8 dequant8(unsigned int dw, __half2 s2, __half2 z2) {
    const __half2 kb = u2h(0x64006400u);   // (1024, 1024)
    U4H8 r;
    unsigned int p0 = (dw & 0x000F000Fu) | 0x64006400u;
    unsigned int p1 = ((dw >> 4)  & 0x000F000Fu) | 0x64006400u;
    unsigned int p2 = ((dw >> 8)  & 0x000F000Fu) | 0x64006400u;
    unsigned int p3 = ((dw >> 12) & 0x000F000Fu) | 0x64006400u;
    r.u.x = h2u(__hfma2(__hsub2(u2h(p0), kb), s2, z2));
    r.u.y = h2u(__hfma2(__hsub2(u2h(p1), kb), s2, z2));
    r.u.z = h2u(__hfma2(__hsub2(u2h(p2), kb), s2, z2));
    r.u.w = h2u(__hfma2(__hsub2(u2h(p3), kb), s2, z2));
    return r.h;
}

// ---------------------------------------------------------------------------
// Kernel 1: x fp32 [512,4096] -> f16 in FRAGMENT-LINEAR order.
// Tile (tm, tk) = rows tm*128..+127 x k tk*64..+63 = 1024 chunks of 16 B.
// Chunk index = (igrp*2 + s01)*64 + q*16 + rlow, where m = tm*128 + igrp*16
// + rlow, k = tk*64 + s01*32 + q*8 + j. A wave's MFMA A-fragment (16 rows x
// one 32-k step) is then chunks [base .. base+63] -> one fully-coalesced
// 1 KB global load per fragment (lane = q*16 + rlow matches A-layout
// m=lane&15, k-octet=lane>>4).
// ---------------------------------------------------------------------------
__global__ __launch_bounds__(256) void cvt_kernel(
        const float* __restrict__ x, unsigned int* __restrict__ xb) {
    int id = blockIdx.x * 256 + threadIdx.x;   // chunk id, 262144 total
    int m  = id >> 9;
    int kc = id & 511;                          // k-octet within row
    const float4* src = (const float4*)(x + ((size_t)m << 12) + (kc << 3));
    float4 f0 = src[0];
    float4 f1 = src[1];
    uint4 v;
    v.x = h2u(__float22half2_rn(float2{f0.x, f0.y}));
    v.y = h2u(__float22half2_rn(float2{f0.z, f0.w}));
    v.z = h2u(__float22half2_rn(float2{f1.x, f1.y}));
    v.w = h2u(__float22half2_rn(float2{f1.z, f1.w}));
    int tm = m >> 7, r = m & 127, tk = kc >> 3, c = kc & 7;
    int igrp = r >> 4, rlow = r & 15, s01 = c >> 2, q = c & 3;
    int chunk = ((igrp * 2 + s01) << 6) + (q << 4) + rlow;
    size_t dstu = (((size_t)(tm * KT + tk)) << 12) + ((size_t)chunk << 2);
    *((uint4*)(xb + dstu)) = v;
}

// ---------------------------------------------------------------------------
// Kernel 2: pack wq int32 [N,K] -> nibbles, tile-major [nb][kt], within tile
// dword index = q*128 + r (q = k-octet 0..7, r = n-row 0..127), nibbles
// pair-interleaved: code 2j -> bits 4j, code 2j+1 -> bits 16+4j. (R5-proven)
// ---------------------------------------------------------------------------
__global__ __launch_bounds__(256) void pack_kernel(
        const int* __restrict__ wq, unsigned int* __restrict__ wpk) {
    int id   = blockIdx.x * 256 + threadIdx.x;
    int tile = id >> 9;                         // 5504 tiles (86 nb x 64 kt)
    int p    = id & 511;
    int nb = tile >> 6, kt = tile & 63;
    int r = p >> 2, q0 = (p & 3) * 2;
    const int4* src = (const int4*)(wq + (size_t)(nb * 128 + r) * K_DIM + kt * 64 + q0 * 8);
    int4 a0 = src[0];
    int4 a1 = src[1];
    int4 a2 = src[2];
    int4 a3 = src[3];
    unsigned int u0 =
        (unsigned)a0.x | ((unsigned)a0.z << 4)  | ((unsigned)a1.x << 8)  | ((unsigned)a1.z << 12) |
        ((unsigned)a0.y << 16) | ((unsigned)a0.w << 20) | ((unsigned)a1.y << 24) | ((unsigned)a1.w << 28);
    unsigned int u1 =
        (unsigned)a2.x | ((unsigned)a2.z << 4)  | ((unsigned)a3.x << 8)  | ((unsigned)a3.z << 12) |
        ((unsigned)a2.y << 16) | ((unsigned)a2.w << 20) | ((unsigned)a3.y << 24) | ((unsigned)a3.w << 28);
    size_t base = ((size_t)tile) << 10;
    wpk[base + (q0 << 7) + r]       = u0;
    wpk[base + ((q0 + 1) << 7) + r] = u1;
}

// ---------------------------------------------------------------------------
// Kernel 3: GEMM. ONE WAVE PER BLOCK, 64x64 tile, 4x4 acc of 16x16x32 f16
// MFMA. No LDS, no __syncthreads, no DMA: A-fragments loaded directly from
// fragment-linear xb (L2-resident); W dequanted in-register from packed
// nibbles (prefetched one k-tile ahead). Split-K=2, atomic-f32 epilogue.
// ---------------------------------------------------------------------------
__global__ __launch_bounds__(64, 3) void gemm_kernel(
        const unsigned int* __restrict__ xb,    // fragment-linear f16 x
        const unsigned int* __restrict__ wpk,   // packed nibbles, [q][r] tiles
        const float*        __restrict__ saz,   // [K/128, N, 2]
        float*              __restrict__ out)   // [M,N] fp32 (pre-zeroed)
{
    const int bx   = blockIdx.x;
    const int mbp  = bx & 7;                   // 64-row strip 0..7
    const int rest = bx >> 3;
    const int nbp  = rest % NB_N;              // 64-col strip 0..171
    const int sk   = rest / NB_N;              // 0..1
    const int kt0  = sk * (KT / SK);
    const int kt1  = kt0 + (KT / SK);          // 32 k-tiles per wave
    const int lane = threadIdx.x;
    const int q4   = lane >> 4;
    const int lr   = lane & 15;

    const int tm    = mbp >> 1;                // xb 128-row tile
    const int igrp0 = (mbp & 1) * 4;           // first 16-row group
    const int nbt   = nbp >> 1;                // wpk 128-col tile
    const int wn    = (nbp & 1) * 64;

    // A fragments: 16 B units; frag (i, s01) at xat[i*128 + s01*64]
    const half8* xat = (const half8*)xb
        + (((size_t)(tm * KT + kt0)) << 10) + (igrp0 << 7) + lane;

    // W: frag (j, s01) at wbase[s01*512 + j*16]; advance 1024 dwords/k-tile
    const unsigned int* wbase =
        wpk + (((size_t)(nbt * KT + kt0)) << 10) + (q4 << 7) + wn + lr;

    const float2* saz2 = (const float2*)saz;
    const int nrow0 = nbp * 64 + lr;           // n-row for frag j: +j*16

    floatx4 acc[4][4];
    floatx4 zero4 = {0.f, 0.f, 0.f, 0.f};
#pragma unroll
    for (int i = 0; i < 4; ++i)
#pragma unroll
        for (int j = 0; j < 4; ++j)
            acc[i][j] = zero4;

    // prologue: W dwords for kt0
    unsigned int qw[8], qwn[8];
#pragma unroll
    for (int f = 0; f < 8; ++f)
        qw[f] = wbase[(f >> 2) * 512 + (f & 3) * 16];

    __half2 s2[4], z2[4];

    for (int kt = kt0; kt < kt1; ++kt) {
        // A loads for THIS iter (consumed below; latency covered by the
        // scale/dequant VALU work and 3 waves/SIMD)
        half8 av[8];
#pragma unroll
        for (int i = 0; i < 4; ++i) {
#pragma unroll
            for (int s = 0; s < 2; ++s)
                av[i * 2 + s] = xat[i * 128 + s * 64];
        }
        xat += 1024;

        // scales: new group every even kt (GS=128 = 2 k-tiles)
        if ((kt & 1) == 0) {
            const size_t gbase = (size_t)(kt >> 1) * N_DIM + nrow0;
#pragma unroll
            for (int t = 0; t < 4; ++t) {
                float2 f = saz2[gbase + t * 16];
                s2[t] = __float2half2_rn(f.x);
                z2[t] = __float2half2_rn(fmaf(-8.f, f.x, f.y));
            }
        }

        // prefetch next k-tile's W (in flight during MFMA)
        if (kt + 1 < kt1) {
            wbase += 1024;
#pragma unroll
            for (int f = 0; f < 8; ++f)
                qwn[f] = wbase[(f >> 2) * 512 + (f & 3) * 16];
        }

        // compute: 2 k-steps of 32; dequant b-frags in registers
#pragma unroll
        for (int s01 = 0; s01 < 2; ++s01) {
#pragma unroll
            for (int j = 0; j < 4; ++j) {
                half8 bv = dequant8(qw[s01 * 4 + j], s2[j], z2[j]);
#pragma unroll
                for (int i = 0; i < 4; ++i)
                    acc[i][j] = __builtin_amdgcn_mfma_f32_16x16x32_f16(
                        av[i * 2 + s01], bv, acc[i][j], 0, 0, 0);
            }
        }

#pragma unroll
        for (int f = 0; f < 8; ++f) qw[f] = qwn[f];
    }

    // Epilogue: C/D layout col = lane&15 (n), row = q4*4 + reg (m).
    const int m0 = mbp * 64 + q4 * 4;
    const int n0 = nbp * 64 + lr;
#pragma unroll
    for (int i = 0; i < 4; ++i) {
#pragma unroll
        for (int j = 0; j < 4; ++j) {
            floatx4 v = acc[i][j];
            float* o = out + (size_t)(m0 + i * 16) * N_DIM + (n0 + j * 16);
#pragma unroll
            for (int rr = 0; rr < 4; ++rr)
                __hip_atomic_fetch_add(&o[(size_t)rr * N_DIM], v[rr],
                                       __ATOMIC_RELAXED, __HIP_MEMORY_SCOPE_AGENT);
        }
    }
}

extern "C" void kernel_launch(void* const* d_in, const int* in_sizes, int n_in,
                              void* d_out, int out_size, void* d_ws, size_t ws_size,
                              hipStream_t stream) {
    const float* x   = (const float*)d_in[0];
    const int*   wq  = (const int*)d_in[1];
    const float* saz = (const float*)d_in[2];

    // ws layout: [wpk: 22,544,384 B packed weights][xb: 4 MB f16 x]
    unsigned int* wpk = (unsigned int*)d_ws;
    unsigned int* xb  = (unsigned int*)((char*)d_ws + 22544384);

    hipMemsetAsync(d_out, 0, (size_t)out_size * sizeof(float), stream);
    pack_kernel<<<dim3(11008), dim3(256), 0, stream>>>(wq, wpk);
    cvt_kernel<<<dim3(1024), dim3(256), 0, stream>>>(x, xb);
    gemm_kernel<<<dim3(NBLK), dim3(64), 0, stream>>>(xb, wpk, saz, (float*)d_out);
}